// Round 3
// baseline (1311.069 us; speedup 1.0000x reference)
//
#include <hip/hip_runtime.h>

#define N_NODES  50000
#define N_EDGES  800000
#define N_GRAPHS 128
#define FDIM     256

// ---------------- degree / CSR build ----------------

__global__ void k_zero(float* deg, int* cnt, int n) {
    int i = blockIdx.x * blockDim.x + threadIdx.x;
    if (i < n) { deg[i] = 0.0f; cnt[i] = 0; }
}

__global__ void k_deg(const int* __restrict__ dst, const float* __restrict__ ea,
                      float* deg, int* cnt, int E) {
    int e = blockIdx.x * blockDim.x + threadIdx.x;
    if (e < E) {
        int d = dst[e];
        atomicAdd(&deg[d], ea[e]);
        atomicAdd(&cnt[d], 1);
    }
}

__global__ void k_dinv(const float* __restrict__ deg, float* dinv, int n) {
    int i = blockIdx.x * blockDim.x + threadIdx.x;
    if (i < n) dinv[i] = rsqrtf(deg[i] + 1.0f);
}

__global__ __launch_bounds__(1024) void k_scan(const int* __restrict__ cnt,
                                               int* row_ptr, int* cursor, int n) {
    __shared__ int buf[2][1024];
    int tid = threadIdx.x;
    int carry = 0;
    for (int base = 0; base < n; base += 1024) {
        int i = base + tid;
        int v = (i < n) ? cnt[i] : 0;
        int pb = 0;
        buf[0][tid] = v;
        __syncthreads();
        for (int off = 1; off < 1024; off <<= 1) {
            int t = buf[pb][tid];
            if (tid >= off) t += buf[pb][tid - off];
            buf[1 - pb][tid] = t;
            pb = 1 - pb;
            __syncthreads();
        }
        int incl = buf[pb][tid];
        if (i < n) { int ex = carry + incl - v; row_ptr[i] = ex; cursor[i] = ex; }
        int tot = buf[pb][1023];
        __syncthreads();
        carry += tot;
    }
    if (tid == 0) row_ptr[n] = carry;
}

__global__ void k_scatter(const int* __restrict__ src, const int* __restrict__ dst,
                          const float* __restrict__ ea,
                          const float* __restrict__ dinv,
                          int* cursor, int* col, float* val, int E) {
    int e = blockIdx.x * blockDim.x + threadIdx.x;
    if (e < E) {
        int d = dst[e];
        int s = src[e];
        int p = atomicAdd(&cursor[d], 1);
        col[p] = s;
        val[p] = ea[e] * dinv[s];   // dinv[dst] factored out per-row
    }
}

// ---------------- aggregation: S[n] = dinv[n]*sum_e val*h[col] + dinv^2*h[n] ----------------
// h = RELU ? relu(H) : H.
template<bool RELU>
__global__ __launch_bounds__(256) void k_agg(const float* __restrict__ H,
                                             const int* __restrict__ rowptr,
                                             const int* __restrict__ col,
                                             const float* __restrict__ val,
                                             const float* __restrict__ dinv,
                                             float* __restrict__ S, int M) {
    int wave = threadIdx.x >> 6;
    int lane = threadIdx.x & 63;
    int n = blockIdx.x * 4 + wave;
    if (n >= M) return;
    int f4 = lane * 4;

    float a0 = 0.f, a1 = 0.f, a2 = 0.f, a3 = 0.f;
    int e0 = rowptr[n], e1 = rowptr[n + 1];
    for (int e = e0; e < e1; e++) {
        int s = col[e];
        float v = val[e];
        float4 h = *(const float4*)(H + (size_t)s * 256 + f4);
        if (RELU) {
            h.x = fmaxf(h.x, 0.f); h.y = fmaxf(h.y, 0.f);
            h.z = fmaxf(h.z, 0.f); h.w = fmaxf(h.w, 0.f);
        }
        a0 = fmaf(v, h.x, a0); a1 = fmaf(v, h.y, a1);
        a2 = fmaf(v, h.z, a2); a3 = fmaf(v, h.w, a3);
    }
    float di = dinv[n];
    float sc = di * di;
    float4 hn = *(const float4*)(H + (size_t)n * 256 + f4);
    if (RELU) {
        hn.x = fmaxf(hn.x, 0.f); hn.y = fmaxf(hn.y, 0.f);
        hn.z = fmaxf(hn.z, 0.f); hn.w = fmaxf(hn.w, 0.f);
    }
    float4 o;
    o.x = fmaf(di, a0, sc * hn.x);
    o.y = fmaf(di, a1, sc * hn.y);
    o.z = fmaf(di, a2, sc * hn.z);
    o.w = fmaf(di, a3, sc * hn.w);
    *(float4*)(S + (size_t)n * 256 + f4) = o;
}

// ---------------- GEMM (in-place): AT[M,256] = AT[M,256] @ W[256,256] + bias ----------------
// Block = 256 threads, tile 32 rows x 256 cols. A-tile in LDS (broadcast reads),
// W streamed coalesced (L2-resident). Each block reads/writes only its own rows.
__global__ __launch_bounds__(256) void k_gemm(float* AT,
                                              const float* __restrict__ W,
                                              const float* __restrict__ bias, int M) {
    __shared__ float Alds[32 * 256];
    int tid = threadIdx.x;
    int rb = blockIdx.x * 32;

    for (int i = tid; i < 32 * 256; i += 256) {
        int r = i >> 8;
        int k = i & 255;
        int row = rb + r;
        Alds[i] = (row < M) ? AT[(size_t)row * 256 + k] : 0.f;
    }
    __syncthreads();

    int colv = tid;
    const float* wcol = W + colv;
    float acc[32];
#pragma unroll
    for (int r = 0; r < 32; r++) acc[r] = 0.f;

#pragma unroll 1
    for (int k = 0; k < 256; k += 4) {
        float w0 = wcol[(size_t)(k + 0) * 256];
        float w1 = wcol[(size_t)(k + 1) * 256];
        float w2 = wcol[(size_t)(k + 2) * 256];
        float w3 = wcol[(size_t)(k + 3) * 256];
#pragma unroll
        for (int r = 0; r < 32; r++) {
            const float4 a = *(const float4*)&Alds[r * 256 + k];
            acc[r] = fmaf(a.x, w0, fmaf(a.y, w1, fmaf(a.z, w2, fmaf(a.w, w3, acc[r]))));
        }
    }

    float bv = bias[colv];
#pragma unroll
    for (int r = 0; r < 32; r++) {
        int row = rb + r;
        if (row < M) AT[(size_t)row * 256 + colv] = acc[r] + bv;
    }
}

// ---------------- mean pool per graph over relu(c3) (batch sorted) ----------------
__global__ __launch_bounds__(1024) void k_pool(const float* __restrict__ C3,
                                               const int* __restrict__ batch, int N,
                                               float* __restrict__ pooled) {
    int g = blockIdx.x;
    __shared__ int range[2];
    __shared__ float part[4][256];
    if (threadIdx.x == 0 && threadIdx.y == 0) {
        int lo = 0, hi = N;
        while (lo < hi) { int mid = (lo + hi) >> 1; if (batch[mid] < g) lo = mid + 1; else hi = mid; }
        range[0] = lo;
        int lo2 = lo, hi2 = N;
        while (lo2 < hi2) { int mid = (lo2 + hi2) >> 1; if (batch[mid] < g + 1) lo2 = mid + 1; else hi2 = mid; }
        range[1] = lo2;
    }
    __syncthreads();
    int start = range[0], end = range[1];
    int f = threadIdx.x;
    float s = 0.f;
    for (int i = start + threadIdx.y; i < end; i += 4)
        s += fmaxf(C3[(size_t)i * 256 + f], 0.f);
    part[threadIdx.y][f] = s;
    __syncthreads();
    if (threadIdx.y == 0) {
        float tot = part[0][f] + part[1][f] + part[2][f] + part[3][f];
        int cnt = end - start;
        pooled[g * 256 + f] = tot / (float)(cnt > 0 ? cnt : 1);
    }
}

// ---------------- tiny MLP head: 256 -> 64 -> 32 -> 2, relu each ----------------
__global__ __launch_bounds__(64) void k_mlp(const float* __restrict__ pooled,
                                            const float* __restrict__ L1w,
                                            const float* __restrict__ L1b,
                                            const float* __restrict__ L2w,
                                            const float* __restrict__ L2b,
                                            const float* __restrict__ L3w,
                                            const float* __restrict__ L3b,
                                            float* __restrict__ out) {
    int g = blockIdx.x;
    int j = threadIdx.x;
    __shared__ float o1[64];
    __shared__ float o2[32];
    float s = L1b[j];
    const float* p = pooled + g * 256;
    for (int k = 0; k < 256; k++) s = fmaf(p[k], L1w[k * 64 + j], s);
    o1[j] = fmaxf(s, 0.f);
    __syncthreads();
    if (j < 32) {
        float s2 = L2b[j];
        for (int k = 0; k < 64; k++) s2 = fmaf(o1[k], L2w[k * 32 + j], s2);
        o2[j] = fmaxf(s2, 0.f);
    }
    __syncthreads();
    if (j < 2) {
        float s3 = L3b[j];
        for (int k = 0; k < 32; k++) s3 = fmaf(o2[k], L3w[k * 2 + j], s3);
        out[g * 2 + j] = fmaxf(s3, 0.f);
    }
}

extern "C" void kernel_launch(void* const* d_in, const int* in_sizes, int n_in,
                              void* d_out, int out_size, void* d_ws, size_t ws_size,
                              hipStream_t stream) {
    const float* x   = (const float*)d_in[0];
    const int*   ei  = (const int*)d_in[1];
    const float* ea  = (const float*)d_in[2];
    const int*   bat = (const int*)d_in[3];
    const float* W1  = (const float*)d_in[4];
    const float* b1  = (const float*)d_in[5];
    const float* W2  = (const float*)d_in[6];
    const float* b2  = (const float*)d_in[7];
    const float* W3  = (const float*)d_in[8];
    const float* b3  = (const float*)d_in[9];
    const float* L1w = (const float*)d_in[10];
    const float* L1b = (const float*)d_in[11];
    const float* L2w = (const float*)d_in[12];
    const float* L2b = (const float*)d_in[13];
    const float* L3w = (const float*)d_in[14];
    const float* L3b = (const float*)d_in[15];

    const int N = N_NODES, E = N_EDGES;
    const int* srcp = ei;
    const int* dstp = ei + E;

    // d_out layout (fp32 elements): out[256] | pooled[32768] | c1 | c2 | c3
    float* out_p    = (float*)d_out;
    float* pooled_p = out_p + 256;
    float* c1_p     = out_p + 33024;
    float* c2_p     = c1_p + (size_t)N * FDIM;
    float* c3_p     = c2_p + (size_t)N * FDIM;

    // workspace carve (bytes) — total ~7.5 MB
    char* ws = (char*)d_ws;
    size_t off = 0;
    float* dinv    = (float*)(ws + off); off += (size_t)N * 4;
    float* deg     = (float*)(ws + off); off += (size_t)N * 4;
    int*   cnt     = (int*)(ws + off);   off += (size_t)N * 4;
    int*   row_ptr = (int*)(ws + off);   off += ((size_t)N + 16) * 4;
    int*   cursor  = (int*)(ws + off);   off += (size_t)N * 4;
    int*   col     = (int*)(ws + off);   off += (size_t)E * 4;
    float* val     = (float*)(ws + off); off += (size_t)E * 4;
    (void)ws_size; (void)n_in; (void)in_sizes; (void)out_size;

    int nb256 = (N + 255) / 256;
    int eb256 = (E + 255) / 256;

    k_zero<<<nb256, 256, 0, stream>>>(deg, cnt, N);
    k_deg<<<eb256, 256, 0, stream>>>(dstp, ea, deg, cnt, E);
    k_dinv<<<nb256, 256, 0, stream>>>(deg, dinv, N);
    k_scan<<<1, 1024, 0, stream>>>(cnt, row_ptr, cursor, N);
    k_scatter<<<eb256, 256, 0, stream>>>(srcp, dstp, ea, dinv, cursor, col, val, E);

    int gemm_blocks = (N + 31) / 32;
    int agg_blocks  = (N + 3) / 4;

    // layer 1: S1 = Agg(x) -> c1 region; c1 = S1@W1 + b1 (in place)
    k_agg<false><<<agg_blocks, 256, 0, stream>>>(x, row_ptr, col, val, dinv, c1_p, N);
    k_gemm<<<gemm_blocks, 256, 0, stream>>>(c1_p, W1, b1, N);
    // layer 2: S2 = Agg(relu(c1)) -> c2 region; c2 = S2@W2 + b2
    k_agg<true><<<agg_blocks, 256, 0, stream>>>(c1_p, row_ptr, col, val, dinv, c2_p, N);
    k_gemm<<<gemm_blocks, 256, 0, stream>>>(c2_p, W2, b2, N);
    // layer 3
    k_agg<true><<<agg_blocks, 256, 0, stream>>>(c2_p, row_ptr, col, val, dinv, c3_p, N);
    k_gemm<<<gemm_blocks, 256, 0, stream>>>(c3_p, W3, b3, N);

    // pool + head
    dim3 pb(256, 4);
    k_pool<<<N_GRAPHS, pb, 0, stream>>>(c3_p, bat, N, pooled_p);
    k_mlp<<<N_GRAPHS, 64, 0, stream>>>(pooled_p, L1w, L1b, L2w, L2b, L3w, L3b, out_p);
}

// Round 4
// 1190.362 us; speedup vs baseline: 1.1014x; 1.1014x over previous
//
#include <hip/hip_runtime.h>

#define N_NODES  50000
#define N_EDGES  800000
#define N_GRAPHS 128
#define FDIM     256

typedef __attribute__((ext_vector_type(8))) short short8;
typedef __attribute__((ext_vector_type(4))) float f32x4;

__device__ __forceinline__ unsigned short f2bf(float f) {
    union { float f; unsigned int u; } v; v.f = f;
    unsigned int x = v.u;
    unsigned int r = (x + 0x7FFFu + ((x >> 16) & 1u)) >> 16;
    return (unsigned short)r;
}

// ---------------- degree / CSR build ----------------

__global__ void k_zero(float* deg, int* cnt, int n) {
    int i = blockIdx.x * blockDim.x + threadIdx.x;
    if (i < n) { deg[i] = 0.0f; cnt[i] = 0; }
}

__global__ void k_deg(const int* __restrict__ dst, const float* __restrict__ ea,
                      float* deg, int* cnt, int E) {
    int e = blockIdx.x * blockDim.x + threadIdx.x;
    if (e < E) {
        int d = dst[e];
        atomicAdd(&deg[d], ea[e]);
        atomicAdd(&cnt[d], 1);
    }
}

__global__ void k_dinv(const float* __restrict__ deg, float* dinv, int n) {
    int i = blockIdx.x * blockDim.x + threadIdx.x;
    if (i < n) dinv[i] = rsqrtf(deg[i] + 1.0f);
}

__global__ __launch_bounds__(1024) void k_scan(const int* __restrict__ cnt,
                                               int* row_ptr, int* cursor, int n) {
    __shared__ int buf[2][1024];
    int tid = threadIdx.x;
    int carry = 0;
    for (int base = 0; base < n; base += 1024) {
        int i = base + tid;
        int v = (i < n) ? cnt[i] : 0;
        int pb = 0;
        buf[0][tid] = v;
        __syncthreads();
        for (int off = 1; off < 1024; off <<= 1) {
            int t = buf[pb][tid];
            if (tid >= off) t += buf[pb][tid - off];
            buf[1 - pb][tid] = t;
            pb = 1 - pb;
            __syncthreads();
        }
        int incl = buf[pb][tid];
        if (i < n) { int ex = carry + incl - v; row_ptr[i] = ex; cursor[i] = ex; }
        int tot = buf[pb][1023];
        __syncthreads();
        carry += tot;
    }
    if (tid == 0) row_ptr[n] = carry;
}

__global__ void k_scatter(const int* __restrict__ src, const int* __restrict__ dst,
                          const float* __restrict__ ea,
                          const float* __restrict__ dinv,
                          int* cursor, int* col, float* val, int E) {
    int e = blockIdx.x * blockDim.x + threadIdx.x;
    if (e < E) {
        int d = dst[e];
        int s = src[e];
        int p = atomicAdd(&cursor[d], 1);
        col[p] = s;
        val[p] = ea[e] * dinv[s];   // dinv[dst] factored out per-row
    }
}

// ---------------- W repack fp32 -> bf16 MFMA B-fragment order ----------------
// B frag for (kstep s, coltile c): lane l holds B[k = s*32 + (l>>4)*8 + j][n = c*16 + (l&15)], j=0..7
__global__ void k_repack(const float* __restrict__ W, unsigned short* __restrict__ Wp) {
    int t = blockIdx.x * blockDim.x + threadIdx.x;  // 65536
    int j = t & 7;
    int l = (t >> 3) & 63;
    int c = (t >> 9) & 15;
    int s = t >> 13;
    int k = s * 32 + ((l >> 4) * 8) + j;
    int n = c * 16 + (l & 15);
    Wp[t] = f2bf(W[k * 256 + n]);
}

// ---------------- aggregation: S[n] = dinv[n]*sum_e val*h[col] + dinv^2*h[n] ----------------
// fp32 math, bf16 output (GEMM A operand).
template<bool RELU>
__global__ __launch_bounds__(256) void k_agg(const float* __restrict__ H,
                                             const int* __restrict__ rowptr,
                                             const int* __restrict__ col,
                                             const float* __restrict__ val,
                                             const float* __restrict__ dinv,
                                             unsigned short* __restrict__ S, int M) {
    int wave = threadIdx.x >> 6;
    int lane = threadIdx.x & 63;
    int n = blockIdx.x * 4 + wave;
    if (n >= M) return;
    int f4 = lane * 4;

    float a0 = 0.f, a1 = 0.f, a2 = 0.f, a3 = 0.f;
    int e0 = rowptr[n], e1 = rowptr[n + 1];
    for (int e = e0; e < e1; e++) {
        int s = col[e];
        float v = val[e];
        float4 h = *(const float4*)(H + (size_t)s * 256 + f4);
        if (RELU) {
            h.x = fmaxf(h.x, 0.f); h.y = fmaxf(h.y, 0.f);
            h.z = fmaxf(h.z, 0.f); h.w = fmaxf(h.w, 0.f);
        }
        a0 = fmaf(v, h.x, a0); a1 = fmaf(v, h.y, a1);
        a2 = fmaf(v, h.z, a2); a3 = fmaf(v, h.w, a3);
    }
    float di = dinv[n];
    float sc = di * di;
    float4 hn = *(const float4*)(H + (size_t)n * 256 + f4);
    if (RELU) {
        hn.x = fmaxf(hn.x, 0.f); hn.y = fmaxf(hn.y, 0.f);
        hn.z = fmaxf(hn.z, 0.f); hn.w = fmaxf(hn.w, 0.f);
    }
    *(ushort4*)(S + (size_t)n * 256 + f4) =
        make_ushort4(f2bf(fmaf(di, a0, sc * hn.x)), f2bf(fmaf(di, a1, sc * hn.y)),
                     f2bf(fmaf(di, a2, sc * hn.z)), f2bf(fmaf(di, a3, sc * hn.w)));
}

// ---------------- MFMA GEMM: C[M,256] = S[M,256](bf16) @ W(bf16,repacked) + bias, fp32 out ----------------
__global__ __launch_bounds__(256) void k_gemm(const unsigned short* __restrict__ S,
                                              const unsigned short* __restrict__ Wp,
                                              const float* __restrict__ bias,
                                              float* __restrict__ C, int M) {
    int wave = threadIdx.x >> 6;
    int lane = threadIdx.x & 63;
    int q    = lane >> 4;
    int m16  = lane & 15;
    int rbase = blockIdx.x * 64 + wave * 16;

    f32x4 acc[16];
#pragma unroll
    for (int i = 0; i < 16; i++) acc[i] = (f32x4){0.f, 0.f, 0.f, 0.f};

    int arow = rbase + m16;
    if (arow >= M) arow = M - 1;              // clamp loads; stores are guarded
    const short8* wp8 = (const short8*)Wp;

    short8 aregs[8];
#pragma unroll
    for (int s = 0; s < 8; s++)
        aregs[s] = *(const short8*)(S + (size_t)arow * 256 + s * 32 + q * 8);

#pragma unroll 1
    for (int s = 0; s < 8; s++) {
#pragma unroll
        for (int c = 0; c < 16; c++) {
            short8 b = wp8[(s * 16 + c) * 64 + lane];
            acc[c] = __builtin_amdgcn_mfma_f32_16x16x32_bf16(aregs[s], b, acc[c], 0, 0, 0);
        }
    }
    // C/D layout: col = lane&15, row = (lane>>4)*4 + reg
    int orow0 = rbase + q * 4;
#pragma unroll
    for (int c = 0; c < 16; c++) {
        int colv = c * 16 + m16;
        float bv = bias[colv];
#pragma unroll
        for (int r = 0; r < 4; r++) {
            int row = orow0 + r;
            if (row < M) C[(size_t)row * 256 + colv] = acc[c][r] + bv;
        }
    }
}

// ---------------- mean pool per graph over relu(c3) (batch sorted) ----------------
__global__ __launch_bounds__(1024) void k_pool(const float* __restrict__ C3,
                                               const int* __restrict__ batch, int N,
                                               float* __restrict__ pooled) {
    int g = blockIdx.x;
    __shared__ int range[2];
    __shared__ float part[4][256];
    if (threadIdx.x == 0 && threadIdx.y == 0) {
        int lo = 0, hi = N;
        while (lo < hi) { int mid = (lo + hi) >> 1; if (batch[mid] < g) lo = mid + 1; else hi = mid; }
        range[0] = lo;
        int lo2 = lo, hi2 = N;
        while (lo2 < hi2) { int mid = (lo2 + hi2) >> 1; if (batch[mid] < g + 1) lo2 = mid + 1; else hi2 = mid; }
        range[1] = lo2;
    }
    __syncthreads();
    int start = range[0], end = range[1];
    int f = threadIdx.x;
    float s = 0.f;
    for (int i = start + threadIdx.y; i < end; i += 4)
        s += fmaxf(C3[(size_t)i * 256 + f], 0.f);
    part[threadIdx.y][f] = s;
    __syncthreads();
    if (threadIdx.y == 0) {
        float tot = part[0][f] + part[1][f] + part[2][f] + part[3][f];
        int cnt = end - start;
        pooled[g * 256 + f] = tot / (float)(cnt > 0 ? cnt : 1);
    }
}

// ---------------- tiny MLP head: 256 -> 64 -> 32 -> 2, relu each ----------------
__global__ __launch_bounds__(64) void k_mlp(const float* __restrict__ pooled,
                                            const float* __restrict__ L1w,
                                            const float* __restrict__ L1b,
                                            const float* __restrict__ L2w,
                                            const float* __restrict__ L2b,
                                            const float* __restrict__ L3w,
                                            const float* __restrict__ L3b,
                                            float* __restrict__ out) {
    int g = blockIdx.x;
    int j = threadIdx.x;
    __shared__ float o1[64];
    __shared__ float o2[32];
    float s = L1b[j];
    const float* p = pooled + g * 256;
    for (int k = 0; k < 256; k++) s = fmaf(p[k], L1w[k * 64 + j], s);
    o1[j] = fmaxf(s, 0.f);
    __syncthreads();
    if (j < 32) {
        float s2 = L2b[j];
        for (int k = 0; k < 64; k++) s2 = fmaf(o1[k], L2w[k * 32 + j], s2);
        o2[j] = fmaxf(s2, 0.f);
    }
    __syncthreads();
    if (j < 2) {
        float s3 = L3b[j];
        for (int k = 0; k < 32; k++) s3 = fmaf(o2[k], L3w[k * 2 + j], s3);
        out[g * 2 + j] = fmaxf(s3, 0.f);
    }
}

extern "C" void kernel_launch(void* const* d_in, const int* in_sizes, int n_in,
                              void* d_out, int out_size, void* d_ws, size_t ws_size,
                              hipStream_t stream) {
    const float* x   = (const float*)d_in[0];
    const int*   ei  = (const int*)d_in[1];
    const float* ea  = (const float*)d_in[2];
    const int*   bat = (const int*)d_in[3];
    const float* W1  = (const float*)d_in[4];
    const float* b1  = (const float*)d_in[5];
    const float* W2  = (const float*)d_in[6];
    const float* b2  = (const float*)d_in[7];
    const float* W3  = (const float*)d_in[8];
    const float* b3  = (const float*)d_in[9];
    const float* L1w = (const float*)d_in[10];
    const float* L1b = (const float*)d_in[11];
    const float* L2w = (const float*)d_in[12];
    const float* L2b = (const float*)d_in[13];
    const float* L3w = (const float*)d_in[14];
    const float* L3b = (const float*)d_in[15];

    const int N = N_NODES, E = N_EDGES;
    const int* srcp = ei;
    const int* dstp = ei + E;

    // d_out layout (fp32 elements): out[256] | pooled[32768] | c1 | c2 | c3
    float* out_p    = (float*)d_out;
    float* pooled_p = out_p + 256;
    float* c1_p     = out_p + 33024;
    float* c2_p     = c1_p + (size_t)N * FDIM;
    float* c3_p     = c2_p + (size_t)N * FDIM;

    // workspace carve (bytes) — total ~34 MB
    char* ws = (char*)d_ws;
    size_t off = 0;
    unsigned short* Sb  = (unsigned short*)(ws + off); off += (size_t)(N + 64) * FDIM * 2;  // 25.6 MB
    unsigned short* Wp1 = (unsigned short*)(ws + off); off += 65536 * 2;
    unsigned short* Wp2 = (unsigned short*)(ws + off); off += 65536 * 2;
    unsigned short* Wp3 = (unsigned short*)(ws + off); off += 65536 * 2;
    float* dinv    = (float*)(ws + off); off += (size_t)N * 4;
    float* deg     = (float*)(ws + off); off += (size_t)N * 4;
    int*   cnt     = (int*)(ws + off);   off += (size_t)N * 4;
    int*   row_ptr = (int*)(ws + off);   off += ((size_t)N + 16) * 4;
    int*   cursor  = (int*)(ws + off);   off += (size_t)N * 4;
    int*   col     = (int*)(ws + off);   off += (size_t)E * 4;
    float* val     = (float*)(ws + off); off += (size_t)E * 4;
    (void)ws_size; (void)n_in; (void)in_sizes; (void)out_size;

    int nb256 = (N + 255) / 256;
    int eb256 = (E + 255) / 256;

    k_zero<<<nb256, 256, 0, stream>>>(deg, cnt, N);
    k_deg<<<eb256, 256, 0, stream>>>(dstp, ea, deg, cnt, E);
    k_dinv<<<nb256, 256, 0, stream>>>(deg, dinv, N);
    k_scan<<<1, 1024, 0, stream>>>(cnt, row_ptr, cursor, N);
    k_scatter<<<eb256, 256, 0, stream>>>(srcp, dstp, ea, dinv, cursor, col, val, E);

    k_repack<<<256, 256, 0, stream>>>(W1, Wp1);
    k_repack<<<256, 256, 0, stream>>>(W2, Wp2);
    k_repack<<<256, 256, 0, stream>>>(W3, Wp3);

    int gemm_blocks = (N + 63) / 64;
    int agg_blocks  = (N + 3) / 4;

    // layer 1: Sb = Agg(x); c1 = Sb@W1 + b1
    k_agg<false><<<agg_blocks, 256, 0, stream>>>(x, row_ptr, col, val, dinv, Sb, N);
    k_gemm<<<gemm_blocks, 256, 0, stream>>>(Sb, Wp1, b1, c1_p, N);
    // layer 2: Sb = Agg(relu(c1)); c2 = Sb@W2 + b2
    k_agg<true><<<agg_blocks, 256, 0, stream>>>(c1_p, row_ptr, col, val, dinv, Sb, N);
    k_gemm<<<gemm_blocks, 256, 0, stream>>>(Sb, Wp2, b2, c2_p, N);
    // layer 3
    k_agg<true><<<agg_blocks, 256, 0, stream>>>(c2_p, row_ptr, col, val, dinv, Sb, N);
    k_gemm<<<gemm_blocks, 256, 0, stream>>>(Sb, Wp3, b3, c3_p, N);

    // pool + head
    dim3 pb(256, 4);
    k_pool<<<N_GRAPHS, pb, 0, stream>>>(c3_p, bat, N, pooled_p);
    k_mlp<<<N_GRAPHS, 64, 0, stream>>>(pooled_p, L1w, L1b, L2w, L2b, L3w, L3b, out_p);
}